// Round 2
// baseline (678.759 us; speedup 1.0000x reference)
//
#include <hip/hip_runtime.h>

// Readout: per-graph softmax-weighted segment sum.
// out[g,f] = sum_{i in g} x[i,f]*exp(x[i,f]) / sum_{i in g} exp(x[i,f])
// node_graph_indices is SORTED -> each graph is a contiguous row range.
// One wave per graph; lane = r*16+q covers 4 rows x 256B = 1024B coalesced
// per load instruction. Stream loop is manually unrolled 4x (rows a, a+4,
// a+8, a+12) so each wave keeps 4 independent dwordx4 loads in flight --
// the round-1 version had 1 outstanding load/wave and was latency-bound
// (~2.3 TB/s); 4x MLP should reach the HBM ceiling.

__device__ __forceinline__ int lower_bound_i32(const int* __restrict__ idx,
                                               int n, int target) {
    int lo = 0, hi = n;
    while (lo < hi) {
        int mid = (lo + hi) >> 1;
        if (idx[mid] < target) lo = mid + 1;
        else hi = mid;
    }
    return lo;
}

__device__ __forceinline__ void accum(float4 v, float4& num, float4& den) {
    float ex = __expf(v.x), ey = __expf(v.y), ez = __expf(v.z), ew = __expf(v.w);
    den.x += ex;        den.y += ey;        den.z += ez;        den.w += ew;
    num.x += v.x * ex;  num.y += v.y * ey;  num.z += v.z * ez;  num.w += v.w * ew;
}

__global__ __launch_bounds__(256) void readout_kernel(
    const float* __restrict__ x,      // (n_atoms, 64)
    const int* __restrict__ gidx,     // (n_atoms,) sorted
    float* __restrict__ out,          // (num_graphs, 64)
    int n_atoms, int num_graphs)
{
    const int wave = threadIdx.x >> 6;          // 4 waves / block
    const int g = blockIdx.x * 4 + wave;        // one graph per wave
    if (g >= num_graphs) return;

    const int lane = threadIdx.x & 63;
    const int r = lane >> 4;                    // row-in-group 0..3
    const int q = lane & 15;                    // float4 quad (features q*4..q*4+3)

    const int start = lower_bound_i32(gidx, n_atoms, g);
    const int end   = lower_bound_i32(gidx, n_atoms, g + 1);

    const float4* __restrict__ xq = (const float4*)x;  // row a -> xq[a*16 + q]

    float4 num0 = make_float4(0.f,0.f,0.f,0.f), den0 = make_float4(0.f,0.f,0.f,0.f);
    float4 num1 = make_float4(0.f,0.f,0.f,0.f), den1 = make_float4(0.f,0.f,0.f,0.f);
    float4 num2 = make_float4(0.f,0.f,0.f,0.f), den2 = make_float4(0.f,0.f,0.f,0.f);
    float4 num3 = make_float4(0.f,0.f,0.f,0.f), den3 = make_float4(0.f,0.f,0.f,0.f);

    int a = start + r;
    // Unrolled: this lane handles rows a, a+4, a+8, a+12 -> 4 independent loads.
    for (; a + 12 < end; a += 16) {
        float4 v0 = xq[(size_t)(a     ) * 16 + q];
        float4 v1 = xq[(size_t)(a +  4) * 16 + q];
        float4 v2 = xq[(size_t)(a +  8) * 16 + q];
        float4 v3 = xq[(size_t)(a + 12) * 16 + q];
        accum(v0, num0, den0);
        accum(v1, num1, den1);
        accum(v2, num2, den2);
        accum(v3, num3, den3);
    }
    // Tail: remaining rows, stride 4.
    for (; a < end; a += 4) {
        float4 v = xq[(size_t)a * 16 + q];
        accum(v, num0, den0);
    }

    num0.x += num1.x + num2.x + num3.x;  den0.x += den1.x + den2.x + den3.x;
    num0.y += num1.y + num2.y + num3.y;  den0.y += den1.y + den2.y + den3.y;
    num0.z += num1.z + num2.z + num3.z;  den0.z += den1.z + den2.z + den3.z;
    num0.w += num1.w + num2.w + num3.w;  den0.w += den1.w + den2.w + den3.w;

    // Reduce across the 4 row-groups (lanes differing in bits 4 and 5).
    #pragma unroll
    for (int off = 16; off <= 32; off <<= 1) {
        num0.x += __shfl_xor(num0.x, off);
        num0.y += __shfl_xor(num0.y, off);
        num0.z += __shfl_xor(num0.z, off);
        num0.w += __shfl_xor(num0.w, off);
        den0.x += __shfl_xor(den0.x, off);
        den0.y += __shfl_xor(den0.y, off);
        den0.z += __shfl_xor(den0.z, off);
        den0.w += __shfl_xor(den0.w, off);
    }

    if (r == 0) {
        float4 o;
        o.x = (den0.x != 0.f) ? num0.x / den0.x : 0.f;
        o.y = (den0.y != 0.f) ? num0.y / den0.y : 0.f;
        o.z = (den0.z != 0.f) ? num0.z / den0.z : 0.f;
        o.w = (den0.w != 0.f) ? num0.w / den0.w : 0.f;
        ((float4*)out)[(size_t)g * 16 + q] = o;   // 16 lanes x 16B = 256B row
    }
}

extern "C" void kernel_launch(void* const* d_in, const int* in_sizes, int n_in,
                              void* d_out, int out_size, void* d_ws, size_t ws_size,
                              hipStream_t stream) {
    const float* x    = (const float*)d_in[0];
    const int*   gidx = (const int*)d_in[1];
    float*       out  = (float*)d_out;

    const int n_atoms    = in_sizes[1];       // 2,000,000
    const int num_graphs = out_size / 64;     // 16384 (F = 64)

    const int blocks = (num_graphs + 3) / 4;  // 4 graphs (waves) per block
    readout_kernel<<<blocks, 256, 0, stream>>>(x, gidx, out, n_atoms, num_graphs);
}

// Round 3
// 628.889 us; speedup vs baseline: 1.0793x; 1.0793x over previous
//
#include <hip/hip_runtime.h>

// Readout: per-graph softmax-weighted segment sum.
// out[g,f] = sum_{i in g} x[i,f]*exp(x[i,f]) / sum_{i in g} exp(x[i,f])
// node_graph_indices is SORTED -> each graph is a contiguous row range.
//
// Phase 1 (offsets_kernel): boundary-scan gidx once (coalesced, ~3us) and
// write starts[16385] into d_ws. Replaces 2x 21-step dependent binary
// searches per wave in the hot kernel (~21us serial latency per wave).
// Phase 2 (readout_kernel): one wave per graph; lane = r*16+q; 8 independent
// nontemporal float4 loads in flight (rows a..a+28 step 4 => 32 rows/iter
// per wave); register accumulation; shfl-xor reduce; 256B row store.

typedef float f4 __attribute__((ext_vector_type(4)));

__global__ __launch_bounds__(256) void offsets_kernel(
    const int* __restrict__ gidx, int* __restrict__ starts,
    int n_atoms, int num_graphs)
{
    int i = blockIdx.x * blockDim.x + threadIdx.x;
    if (i >= n_atoms) return;
    if (i == 0) {
        int b = gidx[0];
        for (int g = 0; g <= b && g < num_graphs; ++g) starts[g] = 0;
        starts[num_graphs] = n_atoms;
    } else {
        int a = gidx[i - 1];
        int b = gidx[i];
        for (int g = a + 1; g <= b && g < num_graphs; ++g) starts[g] = i;
    }
}

__device__ __forceinline__ void accum(f4 v, f4& num, f4& den) {
    f4 e;
    e.x = __expf(v.x); e.y = __expf(v.y); e.z = __expf(v.z); e.w = __expf(v.w);
    den += e;
    num += v * e;
}

__global__ __launch_bounds__(256) void readout_kernel(
    const float* __restrict__ x,        // (n_atoms, 64)
    const int* __restrict__ starts,     // (num_graphs+1,) from phase 1
    float* __restrict__ out,            // (num_graphs, 64)
    int num_graphs)
{
    const int wave = threadIdx.x >> 6;          // 4 waves / block
    const int g = blockIdx.x * 4 + wave;        // one graph per wave
    if (g >= num_graphs) return;

    const int lane = threadIdx.x & 63;
    const int r = lane >> 4;                    // row-in-group 0..3
    const int q = lane & 15;                    // float4 quad (features q*4..q*4+3)

    const int start = starts[g];                // wave-uniform -> s_load
    const int end   = starts[g + 1];

    const f4* __restrict__ xq = (const f4*)x;   // row a -> xq[a*16 + q]

    f4 z = {0.f, 0.f, 0.f, 0.f};
    f4 num0 = z, den0 = z, num1 = z, den1 = z;
    f4 num2 = z, den2 = z, num3 = z, den3 = z;

    int a = start + r;
    // 8 independent NT loads in flight: rows a, a+4, ..., a+28.
    for (; a + 28 < end; a += 32) {
        f4 v0 = __builtin_nontemporal_load(&xq[(size_t)(a     ) * 16 + q]);
        f4 v1 = __builtin_nontemporal_load(&xq[(size_t)(a +  4) * 16 + q]);
        f4 v2 = __builtin_nontemporal_load(&xq[(size_t)(a +  8) * 16 + q]);
        f4 v3 = __builtin_nontemporal_load(&xq[(size_t)(a + 12) * 16 + q]);
        f4 v4 = __builtin_nontemporal_load(&xq[(size_t)(a + 16) * 16 + q]);
        f4 v5 = __builtin_nontemporal_load(&xq[(size_t)(a + 20) * 16 + q]);
        f4 v6 = __builtin_nontemporal_load(&xq[(size_t)(a + 24) * 16 + q]);
        f4 v7 = __builtin_nontemporal_load(&xq[(size_t)(a + 28) * 16 + q]);
        accum(v0, num0, den0); accum(v1, num1, den1);
        accum(v2, num2, den2); accum(v3, num3, den3);
        accum(v4, num0, den0); accum(v5, num1, den1);
        accum(v6, num2, den2); accum(v7, num3, den3);
    }
    // 2x tail.
    for (; a + 4 < end; a += 8) {
        f4 v0 = __builtin_nontemporal_load(&xq[(size_t)(a    ) * 16 + q]);
        f4 v1 = __builtin_nontemporal_load(&xq[(size_t)(a + 4) * 16 + q]);
        accum(v0, num0, den0); accum(v1, num1, den1);
    }
    // 1x tail.
    for (; a < end; a += 4) {
        f4 v = __builtin_nontemporal_load(&xq[(size_t)a * 16 + q]);
        accum(v, num2, den2);
    }

    f4 num = (num0 + num1) + (num2 + num3);
    f4 den = (den0 + den1) + (den2 + den3);

    // Reduce across the 4 row-groups (lanes differing in bits 4 and 5).
    #pragma unroll
    for (int off = 16; off <= 32; off <<= 1) {
        num.x += __shfl_xor(num.x, off);
        num.y += __shfl_xor(num.y, off);
        num.z += __shfl_xor(num.z, off);
        num.w += __shfl_xor(num.w, off);
        den.x += __shfl_xor(den.x, off);
        den.y += __shfl_xor(den.y, off);
        den.z += __shfl_xor(den.z, off);
        den.w += __shfl_xor(den.w, off);
    }

    if (r == 0) {
        f4 o;
        o.x = (den.x != 0.f) ? num.x / den.x : 0.f;
        o.y = (den.y != 0.f) ? num.y / den.y : 0.f;
        o.z = (den.z != 0.f) ? num.z / den.z : 0.f;
        o.w = (den.w != 0.f) ? num.w / den.w : 0.f;
        ((f4*)out)[(size_t)g * 16 + q] = o;     // 16 lanes x 16B = 256B row
    }
}

extern "C" void kernel_launch(void* const* d_in, const int* in_sizes, int n_in,
                              void* d_out, int out_size, void* d_ws, size_t ws_size,
                              hipStream_t stream) {
    const float* x    = (const float*)d_in[0];
    const int*   gidx = (const int*)d_in[1];
    float*       out  = (float*)d_out;
    int*         starts = (int*)d_ws;             // (num_graphs+1) ints

    const int n_atoms    = in_sizes[1];           // 2,000,000
    const int num_graphs = out_size / 64;         // 16384 (F = 64)

    const int blocks1 = (n_atoms + 255) / 256;
    offsets_kernel<<<blocks1, 256, 0, stream>>>(gidx, starts, n_atoms, num_graphs);

    const int blocks2 = (num_graphs + 3) / 4;     // 4 graphs (waves) per block
    readout_kernel<<<blocks2, 256, 0, stream>>>(x, starts, out, num_graphs);
}